// Round 4
// baseline (107.273 us; speedup 1.0000x reference)
//
#include <hip/hip_runtime.h>

typedef unsigned int u32;
typedef unsigned long long u64;

#define BB 16
#define LL 8192
#define CC 512
#define KK 64
#define COLS 16            // columns per block -> 64B (one full line) per row-segment
#define THREADS 1024       // 16 waves; grid 512 blocks = 2 blocks/CU = 32 waves/CU
#define RPI (THREADS / 4)  // 256 rows per iteration
#define NITER (LL / RPI)   // 32
#define CAP 256
#define THRESH 2.1f        // survivors/col: mean~146 sigma~12 -> [64,256] w/ ~7 sigma margin

// ---- order-preserving fp32 <-> u32 key transforms ----
__device__ __forceinline__ u32 flip_bits(u32 u) {
  return u ^ ((u & 0x80000000u) ? 0xFFFFFFFFu : 0x80000000u);
}
__device__ __forceinline__ u32 unflip_bits(u32 f) {
  return (f & 0x80000000u) ? (f ^ 0x80000000u) : ~f;
}
__device__ __forceinline__ u64 u64max(u64 a, u64 b) { return a > b ? a : b; }
__device__ __forceinline__ u64 u64min(u64 a, u64 b) { return a < b ? a : b; }

// Fused single pass: stream 16 columns x 8192 rows per block (x read once).
// Branch-free ballot compaction into per-column LDS candidate lists:
//   ballot -> per-lane slot via popc; ONE batched LDS atomicAdd per column per
//   wave-iteration (lanes 0-3) reserves a slot block; shfl broadcast; survivors
//   do independent exec-masked ds_write_b64. No dependent per-survivor chains.
// Then one wave per column: register bitonic-256 -> top-64 -> index sort -> out.
__global__ __launch_bounds__(THREADS) void kfused(const float* __restrict__ x,
                                                  float* __restrict__ out) {
  __shared__ u64 lists[COLS][CAP];  // 32 KB
  __shared__ u32 cnts[COLS];
  int tid = threadIdx.x;
  int lane = tid & 63;
  int b = blockIdx.x >> 5;          // / (CC/COLS)
  int c0 = (blockIdx.x & 31) * COLS;

  for (int i = tid; i < COLS * CAP; i += THREADS) ((u64*)lists)[i] = 0;
  if (tid < COLS) cnts[tid] = 0;
  __syncthreads();

  // ---- streaming phase ----
  int cg = tid & 3;                 // which float4 within the 16 columns
  int row0 = tid >> 2;              // 0..255
  const float4* p = reinterpret_cast<const float4*>(x + (size_t)b * LL * CC + c0) +
                    cg + (size_t)row0 * (CC / 4);
  const u64 cgmask = 0x1111111111111111ULL << cg;
  const u64 ltmask = (1ULL << lane) - 1ULL;
  int row = row0;
#pragma unroll 4
  for (int i = 0; i < NITER; ++i) {
    float4 v = *p;
    p += RPI * (CC / 4);
    float vs[4] = {v.x, v.y, v.z, v.w};
    bool pr[4];
    u32 pos[4], cnt[4];
#pragma unroll
    for (int q = 0; q < 4; ++q) {
      pr[q] = vs[q] > THRESH;
      u64 m = __ballot(pr[q]) & cgmask;
      pos[q] = (u32)__popcll(m & ltmask);
      cnt[q] = (u32)__popcll(m);
    }
    u32 bs[4] = {0, 0, 0, 0};
    if (lane < 4) {                 // lane L reserves slots for columns L*4+q
#pragma unroll
      for (int q = 0; q < 4; ++q) bs[q] = atomicAdd(&cnts[lane * 4 + q], cnt[q]);
    }
#pragma unroll
    for (int q = 0; q < 4; ++q) {
      u32 base = __shfl(bs[q], cg, 64);
      if (pr[q]) {
        u32 slot = base + pos[q];
        if (slot < CAP)
          lists[cg * 4 + q][slot] =
              (((u64)flip_bits(__float_as_uint(vs[q]))) << 32) | (u32)row;
      }
    }
    row += RPI;
  }
  __syncthreads();

  // ---- select phase: wave w handles column w ----
  int w = tid >> 6;
  const float* colp = x + (size_t)b * LL * CC + (c0 + w);
  u32 total = cnts[w];
  u64 sel;
  if (total >= (u32)KK && total <= (u32)CAP) {
    u64 kk[4];
#pragma unroll
    for (int r = 0; r < 4; ++r) kk[r] = lists[w][r * 64 + lane];
    // bitonic sort 256 keys DESCENDING (registers + shfl)
#pragma unroll
    for (int k = 2; k <= 256; k <<= 1) {
#pragma unroll
      for (int j = k >> 1; j > 0; j >>= 1) {
        if (j >= 64) {
          int rj = j >> 6;
#pragma unroll
          for (int r = 0; r < 4; ++r) {
            int pr2 = r ^ rj;
            if (pr2 > r) {
              int e = r * 64 + lane;
              bool descb = ((e & k) == 0);
              u64 a = kk[r], bq = kk[pr2];
              u64 mx = u64max(a, bq), mn = u64min(a, bq);
              kk[r] = descb ? mx : mn;
              kk[pr2] = descb ? mn : mx;
            }
          }
        } else {
#pragma unroll
          for (int r = 0; r < 4; ++r) {
            u64 other = __shfl_xor(kk[r], j, 64);
            int e = r * 64 + lane;
            bool upper = (lane & j) != 0;
            bool descb = ((e & k) == 0);
            bool keepmax = descb ? !upper : upper;
            kk[r] = keepmax ? u64max(kk[r], other) : u64min(kk[r], other);
          }
        }
      }
    }
    sel = kk[0];  // lane i holds i-th largest key
  } else {
    // exact slow path: 64 rounds of wave-reduce max over keys < prev
    u64 prev = ~0ull;
    sel = 0;
    for (int r = 0; r < KK; ++r) {
      u64 local = 0;
      for (int t = 0; t < LL / 64; ++t) {
        int l = t * 64 + lane;
        float vv = colp[(size_t)l * CC];
        u64 key = (((u64)flip_bits(__float_as_uint(vv))) << 32) | (u32)l;
        if (key < prev) local = u64max(local, key);
      }
#pragma unroll
      for (int m = 32; m > 0; m >>= 1) local = u64max(local, __shfl_xor(local, m, 64));
      if (lane == r) sel = local;
      prev = local;
    }
  }

  // re-key by (index, value), sort ASCENDING -> original sequence order
  u32 f = (u32)(sel >> 32);
  u32 l = (u32)sel;
  u64 s2 = (((u64)l) << 32) | f;
#pragma unroll
  for (int k = 2; k <= 64; k <<= 1) {
#pragma unroll
    for (int j = k >> 1; j > 0; j >>= 1) {
      u64 other = __shfl_xor(s2, j, 64);
      bool upper = (lane & j) != 0;
      bool ascb = ((lane & k) == 0);
      bool keepmax = ascb ? upper : !upper;
      s2 = keepmax ? u64max(s2, other) : u64min(s2, other);
    }
  }
  out[((size_t)b * KK + lane) * CC + (c0 + w)] = __uint_as_float(unflip_bits((u32)s2));
}

extern "C" void kernel_launch(void* const* d_in, const int* in_sizes, int n_in,
                              void* d_out, int out_size, void* d_ws, size_t ws_size,
                              hipStream_t stream) {
  const float* x = (const float*)d_in[0];
  float* out = (float*)d_out;
  kfused<<<BB * (CC / COLS), THREADS, 0, stream>>>(x, out);
}